// Round 14
// baseline (117.881 us; speedup 1.0000x reference)
//
#include <hip/hip_runtime.h>
#include <hip/hip_bf16.h>

// Windowed MHA, B=16 C=128 H=W=128, WINDOW=64, heads=4, d=32.
// R14 = R13 (one wave = one (window,head); 4096 x 256thr; ONE barrier;
// Q/K/V/P all in registers via proven shfl redistribution) +
//   (a) hardware bf16 packing via __float22bfloat162_rn (compiler emits
//       v_cvt_pk_bf16_f32; ~800 -> ~120 VALU ops/thread in packs) — NOT the
//       R6 inline-asm path.
//   (b) s_setprio(1) around MFMA bursts (T5; R13's independent waves give
//       the phase diversity it needs).

typedef __attribute__((ext_vector_type(8))) short bf16x8;
typedef __attribute__((ext_vector_type(4))) float f32x4;

__device__ __forceinline__ ushort f2bf(float f) {
    __hip_bfloat16 h = __float2bfloat16(f);       // RNE
    ushort u; __builtin_memcpy(&u, &h, 2); return u;
}
__device__ __forceinline__ unsigned pk2(float a, float b) {
    __hip_bfloat162 h = __float22bfloat162_rn(make_float2(a, b));  // lo=a, hi=b
    unsigned u; __builtin_memcpy(&u, &h, 4); return u;
}
// 256B-row tile (sX): row bits 0-3 ^ bits 4-5 -> byte bits 4-7.
__device__ __forceinline__ int fsw(int row) { return ((row ^ (row >> 4)) & 15) << 4; }

__global__ void wconv(const float* __restrict__ Wq, const float* __restrict__ Wk,
                      const float* __restrict__ Wv, ushort* __restrict__ out) {
    int i = blockIdx.x * 256 + threadIdx.x;        // 16384 per matrix
    out[i]         = f2bf(Wq[i]);
    out[16384 + i] = f2bf(Wk[i]);
    out[32768 + i] = f2bf(Wv[i]);
}

__global__ __launch_bounds__(256, 2)
void attn_win(const float* __restrict__ x, const ushort* __restrict__ wbf,
              const float* __restrict__ bq, const float* __restrict__ bk,
              const float* __restrict__ bv, const float* __restrict__ Bb,
              float* __restrict__ out) {
    __shared__ __align__(16) char sX[16384];   // the ONLY LDS tenant

    const int tid = threadIdx.x;
    const int w = tid >> 6;          // wave = head (0..3)
    const int l = tid & 63;
    const int lr = l & 15;
    const int lg = (l >> 4) & 3;
    const int blk = blockIdx.x;
    const int b = blk >> 8, n = blk & 255;
    const long xbase = (long)b * 128 * 16384 + n * 64;

    // shfl lane plumbing (R5/R12/R13-proven)
    const int s0 = 32 * (lg & 1) + lr;
    const int s1 = s0 + 16;
    const bool hi2 = (lg >> 1);

    // ---- stage X: 4-channel quads -> packed uint2 ds_writes (2 per thread) ----
    #pragma unroll
    for (int it = 0; it < 2; ++it) {
        int idx = it * 256 + tid;            // 512 items: 32 cq x 16 t4
        int cq = idx >> 4, t4 = idx & 15;
        const float* px = x + xbase + (long)(4 * cq) * 16384 + t4 * 4;
        float4 v0 = *(const float4*)(px);
        float4 v1 = *(const float4*)(px + 16384);
        float4 v2 = *(const float4*)(px + 32768);
        float4 v3 = *(const float4*)(px + 49152);
        float a0[4] = {v0.x, v0.y, v0.z, v0.w};
        float a1[4] = {v1.x, v1.y, v1.z, v1.w};
        float a2[4] = {v2.x, v2.y, v2.z, v2.w};
        float a3[4] = {v3.x, v3.y, v3.z, v3.w};
        #pragma unroll
        for (int jj = 0; jj < 4; ++jj) {
            int t = t4 * 4 + jj;
            uint2 pk;
            pk.x = pk2(a0[jj], a1[jj]);
            pk.y = pk2(a2[jj], a3[jj]);
            *(uint2*)(sX + t * 256 + ((8 * cq) ^ fsw(t))) = pk;
        }
    }
    __syncthreads();   // THE ONLY BARRIER

    // ---- Q,K projections (W.X^T): D[och][tok] -> shfl -> token-major frags ----
    bf16x8 fQ[4], fK[4];
    #pragma unroll
    for (int p = 0; p < 2; ++p) {
        const ushort* wp = wbf + p * 16384;
        const float* bias_p = (p == 0) ? bq : bk;
        f32x4 acc[2][4];   // [tn och-tile][tm tok-tile]; reg r = och 4lg+r
        #pragma unroll
        for (int tn = 0; tn < 2; ++tn) {
            float4 bb = *(const float4*)(bias_p + 32 * w + 16 * tn + 4 * lg);
            #pragma unroll
            for (int tm = 0; tm < 4; ++tm)
                acc[tn][tm] = (f32x4){bb.x, bb.y, bb.z, bb.w};
        }
        #pragma unroll
        for (int kk = 0; kk < 4; ++kk) {
            bf16x8 aXk[4];
            #pragma unroll
            for (int tm = 0; tm < 4; ++tm) {
                int row = 16 * tm + lr;
                aXk[tm] = *(const bf16x8*)(sX + row * 256
                              + (((8 * lg + 32 * kk) * 2) ^ fsw(row)));
            }
            bf16x8 bW[2];
            #pragma unroll
            for (int tn = 0; tn < 2; ++tn)
                bW[tn] = *(const bf16x8*)(wp + (32 * w + 16 * tn + lr) * 128 + 8 * lg + 32 * kk);
            __builtin_amdgcn_s_setprio(1);
            #pragma unroll
            for (int tn = 0; tn < 2; ++tn)
                #pragma unroll
                for (int tm = 0; tm < 4; ++tm)
                    acc[tn][tm] = __builtin_amdgcn_mfma_f32_16x16x32_bf16(
                        bW[tn], aXk[tm], acc[tn][tm], 0, 0, 0);
            __builtin_amdgcn_s_setprio(0);
        }
        unsigned qpk[4][2][2];
        #pragma unroll
        for (int tm = 0; tm < 4; ++tm)
            #pragma unroll
            for (int tn = 0; tn < 2; ++tn) {
                qpk[tm][tn][0] = pk2(acc[tn][tm][0], acc[tn][tm][1]);
                qpk[tm][tn][1] = pk2(acc[tn][tm][2], acc[tn][tm][3]);
            }
        #pragma unroll
        for (int tm = 0; tm < 4; ++tm) {
            int t00 = __shfl((int)qpk[tm][0][0], s0);
            int t01 = __shfl((int)qpk[tm][0][1], s0);
            int t10 = __shfl((int)qpk[tm][1][0], s0);
            int t11 = __shfl((int)qpk[tm][1][1], s0);
            int u00 = __shfl((int)qpk[tm][0][0], s1);
            int u01 = __shfl((int)qpk[tm][0][1], s1);
            int u10 = __shfl((int)qpk[tm][1][0], s1);
            int u11 = __shfl((int)qpk[tm][1][1], s1);
            int4 wv;
            wv.x = hi2 ? t10 : t00;
            wv.y = hi2 ? t11 : t01;
            wv.z = hi2 ? u10 : u00;
            wv.w = hi2 ? u11 : u01;
            if (p == 0) fQ[tm] = *(bf16x8*)&wv;
            else        fK[tm] = *(bf16x8*)&wv;
        }
    }

    // ---- V projection (X.W^T): D[tok][och] -> shfl -> PV B-fragments ----
    bf16x8 fV[2][2];   // [kk2][tn]: lane lr = och, regs = tokens 32kk2+8lg..+7
    {
        const ushort* wp = wbf + 32768;
        f32x4 acc[4][2];   // [tmi tok-tile][tn och-tile]; reg r = token 4lg+r
        #pragma unroll
        for (int tn = 0; tn < 2; ++tn) {
            float bias = bv[32 * w + 16 * tn + lr];
            #pragma unroll
            for (int tmi = 0; tmi < 4; ++tmi)
                acc[tmi][tn] = (f32x4){bias, bias, bias, bias};
        }
        #pragma unroll
        for (int kk = 0; kk < 4; ++kk) {
            bf16x8 aXk[4];
            #pragma unroll
            for (int tmi = 0; tmi < 4; ++tmi) {
                int row = 16 * tmi + lr;
                aXk[tmi] = *(const bf16x8*)(sX + row * 256
                               + (((8 * lg + 32 * kk) * 2) ^ fsw(row)));
            }
            bf16x8 bW[2];
            #pragma unroll
            for (int tn = 0; tn < 2; ++tn)
                bW[tn] = *(const bf16x8*)(wp + (32 * w + 16 * tn + lr) * 128 + 8 * lg + 32 * kk);
            __builtin_amdgcn_s_setprio(1);
            #pragma unroll
            for (int tmi = 0; tmi < 4; ++tmi)
                #pragma unroll
                for (int tn = 0; tn < 2; ++tn)
                    acc[tmi][tn] = __builtin_amdgcn_mfma_f32_16x16x32_bf16(
                        aXk[tmi], bW[tn], acc[tmi][tn], 0, 0, 0);
            __builtin_amdgcn_s_setprio(0);
        }
        unsigned vpk[4][2][2];
        #pragma unroll
        for (int tmi = 0; tmi < 4; ++tmi)
            #pragma unroll
            for (int tn = 0; tn < 2; ++tn) {
                vpk[tmi][tn][0] = pk2(acc[tmi][tn][0], acc[tmi][tn][1]);
                vpk[tmi][tn][1] = pk2(acc[tmi][tn][2], acc[tmi][tn][3]);
            }
        #pragma unroll
        for (int kk2 = 0; kk2 < 2; ++kk2)
            #pragma unroll
            for (int tn = 0; tn < 2; ++tn) {
                int tmA = 2 * kk2, tmB = 2 * kk2 + 1;
                int a0 = __shfl((int)vpk[tmA][tn][0], s0);
                int a1 = __shfl((int)vpk[tmA][tn][1], s0);
                int a2 = __shfl((int)vpk[tmA][tn][0], s1);
                int a3 = __shfl((int)vpk[tmA][tn][1], s1);
                int b0 = __shfl((int)vpk[tmB][tn][0], s0);
                int b1 = __shfl((int)vpk[tmB][tn][1], s0);
                int b2 = __shfl((int)vpk[tmB][tn][0], s1);
                int b3 = __shfl((int)vpk[tmB][tn][1], s1);
                int4 wv;
                wv.x = hi2 ? b0 : a0;
                wv.y = hi2 ? b1 : a1;
                wv.z = hi2 ? b2 : a2;
                wv.w = hi2 ? b3 : a3;
                fV[kk2][tn] = *(bf16x8*)&wv;
            }
    }

    // ---- scores^T = mfma(A=K, B=Q): D[k=16tmK+4lg+r][q=16tmQ+lr] ----
    f32x4 sc[4][4];   // [tmK][tmQ]
    __builtin_amdgcn_s_setprio(1);
    #pragma unroll
    for (int tmK = 0; tmK < 4; ++tmK)
        #pragma unroll
        for (int tmQ = 0; tmQ < 4; ++tmQ) {
            sc[tmK][tmQ] = (f32x4){0.f, 0.f, 0.f, 0.f};
            sc[tmK][tmQ] = __builtin_amdgcn_mfma_f32_16x16x32_bf16(
                fK[tmK], fQ[tmQ], sc[tmK][tmQ], 0, 0, 0);
        }
    __builtin_amdgcn_s_setprio(0);

    // ---- softmax (no max-sub: |score| <~ 0.5); normalize at source ----
    const float scale = 0.17677669529663687f;   // 1/sqrt(32)
    const float L2E = 1.4426950408889634f;
    #pragma unroll
    for (int tmQ = 0; tmQ < 4; ++tmQ) {
        int q = 16 * tmQ + lr;
        float s = 0.f;
        #pragma unroll
        for (int tmK = 0; tmK < 4; ++tmK) {
            float4 bb = *(const float4*)(Bb + q * 64 + 16 * tmK + 4 * lg);
            float e0 = exp2f((sc[tmK][tmQ][0] * scale + bb.x) * L2E);
            float e1 = exp2f((sc[tmK][tmQ][1] * scale + bb.y) * L2E);
            float e2 = exp2f((sc[tmK][tmQ][2] * scale + bb.z) * L2E);
            float e3 = exp2f((sc[tmK][tmQ][3] * scale + bb.w) * L2E);
            sc[tmK][tmQ][0] = e0; sc[tmK][tmQ][1] = e1;
            sc[tmK][tmQ][2] = e2; sc[tmK][tmQ][3] = e3;
            s += (e0 + e1) + (e2 + e3);
        }
        s += __shfl_xor(s, 16);
        s += __shfl_xor(s, 32);
        float rs = 1.0f / s;
        #pragma unroll
        for (int tmK = 0; tmK < 4; ++tmK)
            #pragma unroll
            for (int r = 0; r < 4; ++r)
                sc[tmK][tmQ][r] *= rs;
    }

    // ---- P pack + PV (A-frag via shfl, proven) ----
    unsigned pks[4][4][2];   // [tmK][tmQ][half]
    #pragma unroll
    for (int tmK = 0; tmK < 4; ++tmK)
        #pragma unroll
        for (int tmQ = 0; tmQ < 4; ++tmQ) {
            pks[tmK][tmQ][0] = pk2(sc[tmK][tmQ][0], sc[tmK][tmQ][1]);
            pks[tmK][tmQ][1] = pk2(sc[tmK][tmQ][2], sc[tmK][tmQ][3]);
        }

    f32x4 o[4][2];
    #pragma unroll
    for (int tmq = 0; tmq < 4; ++tmq)
        #pragma unroll
        for (int tn = 0; tn < 2; ++tn)
            o[tmq][tn] = (f32x4){0.f, 0.f, 0.f, 0.f};
    #pragma unroll
    for (int kk2 = 0; kk2 < 2; ++kk2) {
        int tmA = 2 * kk2, tmB = 2 * kk2 + 1;
        #pragma unroll
        for (int tmq = 0; tmq < 4; ++tmq) {
            int a0 = __shfl((int)pks[tmA][tmq][0], s0);
            int b0 = __shfl((int)pks[tmB][tmq][0], s0);
            int a1 = __shfl((int)pks[tmA][tmq][1], s0);
            int b1 = __shfl((int)pks[tmB][tmq][1], s0);
            int a2 = __shfl((int)pks[tmA][tmq][0], s1);
            int b2 = __shfl((int)pks[tmB][tmq][0], s1);
            int a3 = __shfl((int)pks[tmA][tmq][1], s1);
            int b3 = __shfl((int)pks[tmB][tmq][1], s1);
            int4 wv;
            wv.x = hi2 ? b0 : a0;
            wv.y = hi2 ? b1 : a1;
            wv.z = hi2 ? b2 : a2;
            wv.w = hi2 ? b3 : a3;
            bf16x8 aP = *(bf16x8*)&wv;
            __builtin_amdgcn_s_setprio(1);
            #pragma unroll
            for (int tn = 0; tn < 2; ++tn)
                o[tmq][tn] = __builtin_amdgcn_mfma_f32_16x16x32_bf16(
                    aP, fV[kk2][tn], o[tmq][tn], 0, 0, 0);
            __builtin_amdgcn_s_setprio(0);
        }
    }

    // ---- direct coalesced float4 stores (4 consecutive tokens per reg) ----
    #pragma unroll
    for (int tmq = 0; tmq < 4; ++tmq)
        #pragma unroll
        for (int tn = 0; tn < 2; ++tn) {
            int ch = 32 * w + 16 * tn + lr;
            int tok = 16 * tmq + 4 * lg;
            float4 ov;
            ov.x = o[tmq][tn][0];
            ov.y = o[tmq][tn][1];
            ov.z = o[tmq][tn][2];
            ov.w = o[tmq][tn][3];
            *(float4*)(out + xbase + (long)ch * 16384 + tok) = ov;
        }
}

extern "C" void kernel_launch(void* const* d_in, const int* in_sizes, int n_in,
                              void* d_out, int out_size, void* d_ws, size_t ws_size,
                              hipStream_t stream) {
    const float* x  = (const float*)d_in[0];
    const float* Wq = (const float*)d_in[1];
    const float* bq = (const float*)d_in[2];
    const float* Wk = (const float*)d_in[3];
    const float* bk = (const float*)d_in[4];
    const float* Wv = (const float*)d_in[5];
    const float* bv = (const float*)d_in[6];
    const float* Bb = (const float*)d_in[7];
    float* out = (float*)d_out;
    ushort* wbf = (ushort*)d_ws;   // 3 x 128x128 bf16 = 96 KB

    wconv<<<64, 256, 0, stream>>>(Wq, Wk, Wv, wbf);
    attn_win<<<4096, 256, 0, stream>>>(x, wbf, bq, bk, bv, Bb, out);
}

// Round 15
// 114.272 us; speedup vs baseline: 1.0316x; 1.0316x over previous
//
#include <hip/hip_runtime.h>
#include <hip/hip_bf16.h>

// Windowed MHA, B=16 C=128 H=W=128, WINDOW=64, heads=4, d=32.
// R15 = R14 minus s_setprio (suspected small negative; T5 prerequisite absent)
//     + fused Q/K projection kk-loop: shared aXk LDS reads (32->16) and
//       16 independent MFMA accumulators per kk (2x in-wave ILP).
// One wave = one (window, head); 4096 x 256thr; ONE barrier; Q/K/V/P in
// registers via proven shfl redistribution; HW bf16 packing (R14-proven).

typedef __attribute__((ext_vector_type(8))) short bf16x8;
typedef __attribute__((ext_vector_type(4))) float f32x4;

__device__ __forceinline__ ushort f2bf(float f) {
    __hip_bfloat16 h = __float2bfloat16(f);       // RNE
    ushort u; __builtin_memcpy(&u, &h, 2); return u;
}
__device__ __forceinline__ unsigned pk2(float a, float b) {
    __hip_bfloat162 h = __float22bfloat162_rn(make_float2(a, b));  // lo=a, hi=b
    unsigned u; __builtin_memcpy(&u, &h, 4); return u;
}
// 256B-row tile (sX): row bits 0-3 ^ bits 4-5 -> byte bits 4-7.
__device__ __forceinline__ int fsw(int row) { return ((row ^ (row >> 4)) & 15) << 4; }

__global__ void wconv(const float* __restrict__ Wq, const float* __restrict__ Wk,
                      const float* __restrict__ Wv, ushort* __restrict__ out) {
    int i = blockIdx.x * 256 + threadIdx.x;        // 16384 per matrix
    out[i]         = f2bf(Wq[i]);
    out[16384 + i] = f2bf(Wk[i]);
    out[32768 + i] = f2bf(Wv[i]);
}

__global__ __launch_bounds__(256, 2)
void attn_win(const float* __restrict__ x, const ushort* __restrict__ wbf,
              const float* __restrict__ bq, const float* __restrict__ bk,
              const float* __restrict__ bv, const float* __restrict__ Bb,
              float* __restrict__ out) {
    __shared__ __align__(16) char sX[16384];   // the ONLY LDS tenant

    const int tid = threadIdx.x;
    const int w = tid >> 6;          // wave = head (0..3)
    const int l = tid & 63;
    const int lr = l & 15;
    const int lg = (l >> 4) & 3;
    const int blk = blockIdx.x;
    const int b = blk >> 8, n = blk & 255;
    const long xbase = (long)b * 128 * 16384 + n * 64;

    // shfl lane plumbing (R5/R12/R13-proven)
    const int s0 = 32 * (lg & 1) + lr;
    const int s1 = s0 + 16;
    const bool hi2 = (lg >> 1);

    // ---- stage X: 4-channel quads -> packed uint2 ds_writes (2 per thread) ----
    #pragma unroll
    for (int it = 0; it < 2; ++it) {
        int idx = it * 256 + tid;            // 512 items: 32 cq x 16 t4
        int cq = idx >> 4, t4 = idx & 15;
        const float* px = x + xbase + (long)(4 * cq) * 16384 + t4 * 4;
        float4 v0 = *(const float4*)(px);
        float4 v1 = *(const float4*)(px + 16384);
        float4 v2 = *(const float4*)(px + 32768);
        float4 v3 = *(const float4*)(px + 49152);
        float a0[4] = {v0.x, v0.y, v0.z, v0.w};
        float a1[4] = {v1.x, v1.y, v1.z, v1.w};
        float a2[4] = {v2.x, v2.y, v2.z, v2.w};
        float a3[4] = {v3.x, v3.y, v3.z, v3.w};
        #pragma unroll
        for (int jj = 0; jj < 4; ++jj) {
            int t = t4 * 4 + jj;
            uint2 pk;
            pk.x = pk2(a0[jj], a1[jj]);
            pk.y = pk2(a2[jj], a3[jj]);
            *(uint2*)(sX + t * 256 + ((8 * cq) ^ fsw(t))) = pk;
        }
    }
    __syncthreads();   // THE ONLY BARRIER

    // ---- Q,K projections FUSED (W.X^T): shared aXk, 16 indep accumulators ----
    bf16x8 fQ[4], fK[4];
    {
        f32x4 accQ[2][4], accK[2][4];   // [tn och-tile][tm tok-tile]
        #pragma unroll
        for (int tn = 0; tn < 2; ++tn) {
            float4 bbq = *(const float4*)(bq + 32 * w + 16 * tn + 4 * lg);
            float4 bbk = *(const float4*)(bk + 32 * w + 16 * tn + 4 * lg);
            #pragma unroll
            for (int tm = 0; tm < 4; ++tm) {
                accQ[tn][tm] = (f32x4){bbq.x, bbq.y, bbq.z, bbq.w};
                accK[tn][tm] = (f32x4){bbk.x, bbk.y, bbk.z, bbk.w};
            }
        }
        #pragma unroll
        for (int kk = 0; kk < 4; ++kk) {
            bf16x8 aXk[4];
            #pragma unroll
            for (int tm = 0; tm < 4; ++tm) {
                int row = 16 * tm + lr;
                aXk[tm] = *(const bf16x8*)(sX + row * 256
                              + (((8 * lg + 32 * kk) * 2) ^ fsw(row)));
            }
            bf16x8 bWq[2], bWk[2];
            #pragma unroll
            for (int tn = 0; tn < 2; ++tn) {
                int orow = (32 * w + 16 * tn + lr) * 128 + 8 * lg + 32 * kk;
                bWq[tn] = *(const bf16x8*)(wbf + orow);
                bWk[tn] = *(const bf16x8*)(wbf + 16384 + orow);
            }
            #pragma unroll
            for (int tn = 0; tn < 2; ++tn)
                #pragma unroll
                for (int tm = 0; tm < 4; ++tm) {
                    accQ[tn][tm] = __builtin_amdgcn_mfma_f32_16x16x32_bf16(
                        bWq[tn], aXk[tm], accQ[tn][tm], 0, 0, 0);
                    accK[tn][tm] = __builtin_amdgcn_mfma_f32_16x16x32_bf16(
                        bWk[tn], aXk[tm], accK[tn][tm], 0, 0, 0);
                }
        }
        // pack + shfl -> token-major fragments (lane lr = token, regs = 8 ch)
        #pragma unroll
        for (int p = 0; p < 2; ++p) {
            unsigned qpk[4][2][2];
            #pragma unroll
            for (int tm = 0; tm < 4; ++tm)
                #pragma unroll
                for (int tn = 0; tn < 2; ++tn) {
                    const f32x4& a = (p == 0) ? accQ[tn][tm] : accK[tn][tm];
                    qpk[tm][tn][0] = pk2(a[0], a[1]);
                    qpk[tm][tn][1] = pk2(a[2], a[3]);
                }
            #pragma unroll
            for (int tm = 0; tm < 4; ++tm) {
                int t00 = __shfl((int)qpk[tm][0][0], s0);
                int t01 = __shfl((int)qpk[tm][0][1], s0);
                int t10 = __shfl((int)qpk[tm][1][0], s0);
                int t11 = __shfl((int)qpk[tm][1][1], s0);
                int u00 = __shfl((int)qpk[tm][0][0], s1);
                int u01 = __shfl((int)qpk[tm][0][1], s1);
                int u10 = __shfl((int)qpk[tm][1][0], s1);
                int u11 = __shfl((int)qpk[tm][1][1], s1);
                int4 wv;
                wv.x = hi2 ? t10 : t00;
                wv.y = hi2 ? t11 : t01;
                wv.z = hi2 ? u10 : u00;
                wv.w = hi2 ? u11 : u01;
                if (p == 0) fQ[tm] = *(bf16x8*)&wv;
                else        fK[tm] = *(bf16x8*)&wv;
            }
        }
    }

    // ---- V projection (X.W^T): D[tok][och] -> shfl -> PV B-fragments ----
    bf16x8 fV[2][2];   // [kk2][tn]: lane lr = och, regs = tokens 32kk2+8lg..+7
    {
        const ushort* wp = wbf + 32768;
        f32x4 acc[4][2];   // [tmi tok-tile][tn och-tile]; reg r = token 4lg+r
        #pragma unroll
        for (int tn = 0; tn < 2; ++tn) {
            float bias = bv[32 * w + 16 * tn + lr];
            #pragma unroll
            for (int tmi = 0; tmi < 4; ++tmi)
                acc[tmi][tn] = (f32x4){bias, bias, bias, bias};
        }
        #pragma unroll
        for (int kk = 0; kk < 4; ++kk) {
            bf16x8 aXk[4];
            #pragma unroll
            for (int tmi = 0; tmi < 4; ++tmi) {
                int row = 16 * tmi + lr;
                aXk[tmi] = *(const bf16x8*)(sX + row * 256
                               + (((8 * lg + 32 * kk) * 2) ^ fsw(row)));
            }
            bf16x8 bW[2];
            #pragma unroll
            for (int tn = 0; tn < 2; ++tn)
                bW[tn] = *(const bf16x8*)(wp + (32 * w + 16 * tn + lr) * 128 + 8 * lg + 32 * kk);
            #pragma unroll
            for (int tmi = 0; tmi < 4; ++tmi)
                #pragma unroll
                for (int tn = 0; tn < 2; ++tn)
                    acc[tmi][tn] = __builtin_amdgcn_mfma_f32_16x16x32_bf16(
                        aXk[tmi], bW[tn], acc[tmi][tn], 0, 0, 0);
        }
        unsigned vpk[4][2][2];
        #pragma unroll
        for (int tmi = 0; tmi < 4; ++tmi)
            #pragma unroll
            for (int tn = 0; tn < 2; ++tn) {
                vpk[tmi][tn][0] = pk2(acc[tmi][tn][0], acc[tmi][tn][1]);
                vpk[tmi][tn][1] = pk2(acc[tmi][tn][2], acc[tmi][tn][3]);
            }
        #pragma unroll
        for (int kk2 = 0; kk2 < 2; ++kk2)
            #pragma unroll
            for (int tn = 0; tn < 2; ++tn) {
                int tmA = 2 * kk2, tmB = 2 * kk2 + 1;
                int a0 = __shfl((int)vpk[tmA][tn][0], s0);
                int a1 = __shfl((int)vpk[tmA][tn][1], s0);
                int a2 = __shfl((int)vpk[tmA][tn][0], s1);
                int a3 = __shfl((int)vpk[tmA][tn][1], s1);
                int b0 = __shfl((int)vpk[tmB][tn][0], s0);
                int b1 = __shfl((int)vpk[tmB][tn][1], s0);
                int b2 = __shfl((int)vpk[tmB][tn][0], s1);
                int b3 = __shfl((int)vpk[tmB][tn][1], s1);
                int4 wv;
                wv.x = hi2 ? b0 : a0;
                wv.y = hi2 ? b1 : a1;
                wv.z = hi2 ? b2 : a2;
                wv.w = hi2 ? b3 : a3;
                fV[kk2][tn] = *(bf16x8*)&wv;
            }
    }

    // ---- scores^T = mfma(A=K, B=Q): D[k=16tmK+4lg+r][q=16tmQ+lr] ----
    f32x4 sc[4][4];   // [tmK][tmQ]
    #pragma unroll
    for (int tmK = 0; tmK < 4; ++tmK)
        #pragma unroll
        for (int tmQ = 0; tmQ < 4; ++tmQ) {
            sc[tmK][tmQ] = (f32x4){0.f, 0.f, 0.f, 0.f};
            sc[tmK][tmQ] = __builtin_amdgcn_mfma_f32_16x16x32_bf16(
                fK[tmK], fQ[tmQ], sc[tmK][tmQ], 0, 0, 0);
        }

    // ---- softmax (no max-sub: |score| <~ 0.5); normalize at source ----
    const float scale = 0.17677669529663687f;   // 1/sqrt(32)
    const float L2E = 1.4426950408889634f;
    #pragma unroll
    for (int tmQ = 0; tmQ < 4; ++tmQ) {
        int q = 16 * tmQ + lr;
        float s = 0.f;
        #pragma unroll
        for (int tmK = 0; tmK < 4; ++tmK) {
            float4 bb = *(const float4*)(Bb + q * 64 + 16 * tmK + 4 * lg);
            float e0 = exp2f((sc[tmK][tmQ][0] * scale + bb.x) * L2E);
            float e1 = exp2f((sc[tmK][tmQ][1] * scale + bb.y) * L2E);
            float e2 = exp2f((sc[tmK][tmQ][2] * scale + bb.z) * L2E);
            float e3 = exp2f((sc[tmK][tmQ][3] * scale + bb.w) * L2E);
            sc[tmK][tmQ][0] = e0; sc[tmK][tmQ][1] = e1;
            sc[tmK][tmQ][2] = e2; sc[tmK][tmQ][3] = e3;
            s += (e0 + e1) + (e2 + e3);
        }
        s += __shfl_xor(s, 16);
        s += __shfl_xor(s, 32);
        float rs = 1.0f / s;
        #pragma unroll
        for (int tmK = 0; tmK < 4; ++tmK)
            #pragma unroll
            for (int r = 0; r < 4; ++r)
                sc[tmK][tmQ][r] *= rs;
    }

    // ---- P pack + PV (A-frag via shfl, proven) ----
    unsigned pks[4][4][2];   // [tmK][tmQ][half]
    #pragma unroll
    for (int tmK = 0; tmK < 4; ++tmK)
        #pragma unroll
        for (int tmQ = 0; tmQ < 4; ++tmQ) {
            pks[tmK][tmQ][0] = pk2(sc[tmK][tmQ][0], sc[tmK][tmQ][1]);
            pks[tmK][tmQ][1] = pk2(sc[tmK][tmQ][2], sc[tmK][tmQ][3]);
        }

    f32x4 o[4][2];
    #pragma unroll
    for (int tmq = 0; tmq < 4; ++tmq)
        #pragma unroll
        for (int tn = 0; tn < 2; ++tn)
            o[tmq][tn] = (f32x4){0.f, 0.f, 0.f, 0.f};
    #pragma unroll
    for (int kk2 = 0; kk2 < 2; ++kk2) {
        int tmA = 2 * kk2, tmB = 2 * kk2 + 1;
        #pragma unroll
        for (int tmq = 0; tmq < 4; ++tmq) {
            int a0 = __shfl((int)pks[tmA][tmq][0], s0);
            int b0 = __shfl((int)pks[tmB][tmq][0], s0);
            int a1 = __shfl((int)pks[tmA][tmq][1], s0);
            int b1 = __shfl((int)pks[tmB][tmq][1], s0);
            int a2 = __shfl((int)pks[tmA][tmq][0], s1);
            int b2 = __shfl((int)pks[tmB][tmq][0], s1);
            int a3 = __shfl((int)pks[tmA][tmq][1], s1);
            int b3 = __shfl((int)pks[tmB][tmq][1], s1);
            int4 wv;
            wv.x = hi2 ? b0 : a0;
            wv.y = hi2 ? b1 : a1;
            wv.z = hi2 ? b2 : a2;
            wv.w = hi2 ? b3 : a3;
            bf16x8 aP = *(bf16x8*)&wv;
            #pragma unroll
            for (int tn = 0; tn < 2; ++tn)
                o[tmq][tn] = __builtin_amdgcn_mfma_f32_16x16x32_bf16(
                    aP, fV[kk2][tn], o[tmq][tn], 0, 0, 0);
        }
    }

    // ---- direct coalesced float4 stores (4 consecutive tokens per reg) ----
    #pragma unroll
    for (int tmq = 0; tmq < 4; ++tmq)
        #pragma unroll
        for (int tn = 0; tn < 2; ++tn) {
            int ch = 32 * w + 16 * tn + lr;
            int tok = 16 * tmq + 4 * lg;
            float4 ov;
            ov.x = o[tmq][tn][0];
            ov.y = o[tmq][tn][1];
            ov.z = o[tmq][tn][2];
            ov.w = o[tmq][tn][3];
            *(float4*)(out + xbase + (long)ch * 16384 + tok) = ov;
        }
}

extern "C" void kernel_launch(void* const* d_in, const int* in_sizes, int n_in,
                              void* d_out, int out_size, void* d_ws, size_t ws_size,
                              hipStream_t stream) {
    const float* x  = (const float*)d_in[0];
    const float* Wq = (const float*)d_in[1];
    const float* bq = (const float*)d_in[2];
    const float* Wk = (const float*)d_in[3];
    const float* bk = (const float*)d_in[4];
    const float* Wv = (const float*)d_in[5];
    const float* bv = (const float*)d_in[6];
    const float* Bb = (const float*)d_in[7];
    float* out = (float*)d_out;
    ushort* wbf = (ushort*)d_ws;   // 3 x 128x128 bf16 = 96 KB

    wconv<<<64, 256, 0, stream>>>(Wq, Wk, Wv, wbf);
    attn_win<<<4096, 256, 0, stream>>>(x, wbf, bq, bk, bv, Bb, out);
}